// Round 5
// baseline (2059.079 us; speedup 1.0000x reference)
//
#include <hip/hip_runtime.h>
#include <stdint.h>
#include <stddef.h>

#define NEGF (-1.0e30f)
#define LOGK 8.31776616672f  // log(4096)

typedef _Float16 f16x8 __attribute__((ext_vector_type(8)));
typedef float f32x4 __attribute__((ext_vector_type(4)));

constexpr int Bn = 32;
constexpr int Tn = 2000;
constexpr int Cn = 256;
constexpr int Un = 200;
constexpr int Sn = 2 * Un + 1;  // 401
constexpr float Kn = 4096.0f;
constexpr int ROWP = 264;  // f16 row stride: 528B = 33*16 -> rotates bank groups

template <int CTRL>
__device__ __forceinline__ float dppf(float x) {
  int xi = __builtin_bit_cast(int, x);
  int y = __builtin_amdgcn_update_dpp(0, xi, CTRL, 0xF, 0xF, false);
  return __builtin_bit_cast(float, y);
}
#define dpp_x1(v) dppf<0xB1>(v)   // quad_perm(1,0,3,2): lane^1
#define dpp_x2(v) dppf<0x4E>(v)   // quad_perm(2,3,0,1): lane^2
#define dpp_x7(v) dppf<0x141>(v)  // row_half_mirror:    lane^7
#define dpp_x8(v) dppf<0x128>(v)  // row_ror:8:          lane^8 (in 16-row)

__device__ __forceinline__ float lse3(float a, float b, float c) {
  float m = fmaxf(fmaxf(a, b), c);
  return m + __logf(__expf(a - m) + __expf(b - m) + __expf(c - m));
}

__device__ __forceinline__ int clampi(int v, int lo, int hi) {
  return v < lo ? lo : (v > hi ? hi : v);
}

// 34 blocks x 512 threads. Blocks 0-1: MFMA-batched denominator (16 b each).
// Blocks 2-33: CTC numerator (1 b each). VALU dot2 path capped at 1024cy/step/b
// (64K MACs @ 64 MACs/cy/CU); MFMA does the same in ~516cy for 16 b's at once.
__global__ __launch_bounds__(512) void fwd_kernel(
    const float* __restrict__ logp, const int* __restrict__ targets,
    const int* __restrict__ in_lens, const int* __restrict__ tgt_lens,
    const float* __restrict__ trans, const float* __restrict__ start,
    float* __restrict__ ws) {
  const int tid = threadIdx.x;
  const int bid = blockIdx.x;

  if (bid < 2) {
    // ================== denominator: exp-domain batched MFMA ==================
    const int b0 = 16 * bid;
    const int w = tid >> 6;     // wave 0..7: owns cols [32w, 32w+32)
    const int lane = tid & 63;
    const int low = lane & 15;  // A-row m / C-col / B-col-in-tile
    const int q8 = lane >> 4;   // k-quad; C-rows = 4*q8 + reg

    __shared__ __align__(16) _Float16 st[2][16][ROWP];  // alpha (exp domain, f16)
    __shared__ float Rp[16][8];   // per-wave raw-sum partials
    __shared__ float iKZ[16];     // K / Z_b
    __shared__ float Zacc[16];

    int Lr[4];
#pragma unroll
    for (int r = 0; r < 4; ++r) Lr[r] = clampi(in_lens[b0 + 4 * q8 + r], Sn, Tn);
    const int Lown = (tid < 16) ? clampi(in_lens[b0 + tid], Sn, Tn) : 0;
    int Lmax = Sn;
    for (int bb = 0; bb < 16; ++bb)
      Lmax = max(Lmax, clampi(in_lens[b0 + bb], Sn, Tn));

    // B-fragments of E = exp(trans): frag (T,KK): lane holds E[k][n],
    // k = 32*KK + 8*q8 + j (j=0..7), n = 32*w + 16*T + low.  16 named SSA vars.
#define E1(T, KK, J)                                                       \
  (_Float16)__expf(trans[(32 * (KK) + 8 * q8 + (J)) * Cn + (32 * w + 16 * (T) + low)])
#define EB(T, KK)                                                          \
  (f16x8){E1(T, KK, 0), E1(T, KK, 1), E1(T, KK, 2), E1(T, KK, 3),          \
          E1(T, KK, 4), E1(T, KK, 5), E1(T, KK, 6), E1(T, KK, 7)}
    const f16x8 B00 = EB(0, 0), B01 = EB(0, 1), B02 = EB(0, 2), B03 = EB(0, 3);
    const f16x8 B04 = EB(0, 4), B05 = EB(0, 5), B06 = EB(0, 6), B07 = EB(0, 7);
    const f16x8 B10 = EB(1, 0), B11 = EB(1, 1), B12 = EB(1, 2), B13 = EB(1, 3);
    const f16x8 B14 = EB(1, 4), B15 = EB(1, 5), B16 = EB(1, 6), B17 = EB(1, 7);
#undef EB
#undef E1

    // ---- init t=0: st = K*exp(start + lp0); Z_0 via LDS atomic reduce ----
    if (tid < 16) Zacc[tid] = 0.f;
    __syncthreads();
    {
      const int ib = tid >> 5;          // b-row 0..15
      const int ii = (tid & 31) * 8;    // 8 contiguous classes
      const float* lp0 = logp + (size_t)(b0 + ib) * Tn * Cn;
      float zp = 0.f;
#pragma unroll
      for (int rr = 0; rr < 8; ++rr) {
        float v = Kn * __expf(start[ii + rr] + lp0[ii + rr]);
        st[0][ib][ii + rr] = (_Float16)v;
        zp += v;
      }
      atomicAdd(&Zacc[ib], zp);
    }
    __syncthreads();
    float Gown = -LOGK, Zown = 1.f;
    if (tid < 16) {
      Zown = Zacc[tid];
      iKZ[tid] = Kn / Zown;
    }

    // ---- emission pipeline: 8 (b,col) pairs per lane, 2 steps deep ----
    const int colA = 32 * w + low, colB = colA + 16;
    const float* eb[8];
    float pc[8], lpn[8];
#pragma unroll
    for (int i = 0; i < 8; ++i) {
      const int r = i & 3, col = (i >= 4) ? colB : colA;
      eb[i] = logp + (size_t)(b0 + 4 * q8 + r) * Tn * Cn + col;
    }
#pragma unroll
    for (int i = 0; i < 8; ++i) pc[i] = __expf(eb[i][Cn]);  // t=1
    {
      const int t2 = (2 < Lmax) ? 2 : Lmax - 1;
#pragma unroll
      for (int i = 0; i < 8; ++i) lpn[i] = eb[i][(size_t)t2 * Cn];
    }
    __syncthreads();  // covers st[0], iKZ init

    int cur = 0;
    for (int t = 1; t < Lmax; ++t) {
      const int nxt = cur ^ 1;

      // --- MFMA phase: D[b][j] = sum_i st[b][i] * E[i][j], two 16-col tiles ---
      f32x4 c0 = {0.f, 0.f, 0.f, 0.f}, c1 = {0.f, 0.f, 0.f, 0.f};
#define KSTEP(KK, BT0, BT1)                                                \
  {                                                                        \
    const f16x8 a = *(const f16x8*)&st[cur][low][32 * KK + 8 * q8];        \
    c0 = __builtin_amdgcn_mfma_f32_16x16x32_f16(a, BT0, c0, 0, 0, 0);      \
    c1 = __builtin_amdgcn_mfma_f32_16x16x32_f16(a, BT1, c1, 0, 0, 0);      \
  }
      KSTEP(0, B00, B10) KSTEP(1, B01, B11) KSTEP(2, B02, B12)
      KSTEP(3, B03, B13) KSTEP(4, B04, B14) KSTEP(5, B05, B15)
      KSTEP(6, B06, B16) KSTEP(7, B07, B17)
#undef KSTEP

      // --- raw = D * p;  R_b = sum_j raw (butterfly over 16 cols, all-DPP) ---
      float raw0[4], raw1[4], Rr[4];
#pragma unroll
      for (int r = 0; r < 4; ++r) {
        raw0[r] = c0[r] * pc[r];
        raw1[r] = c1[r] * pc[4 + r];
        float x = raw0[r] + raw1[r];
        x += dpp_x1(x);
        x += dpp_x2(x);
        x += dpp_x7(x);
        x += dpp_x8(x);  // masks {1,2,7,8} span the low nibble
        Rr[r] = x;
      }
      if (low == 0) {
#pragma unroll
        for (int r = 0; r < 4; ++r) Rp[4 * q8 + r][w] = Rr[r];
      }

      // --- normalize by K/Z (current) and write st[nxt]; freeze = exact copy ---
#pragma unroll
      for (int r = 0; r < 4; ++r) {
        const int brow = 4 * q8 + r;
        const float kz = iKZ[brow];
        float v0 = raw0[r] * kz, v1 = raw1[r] * kz;
        if (t >= Lr[r]) {
          v0 = (float)st[cur][brow][colA];
          v1 = (float)st[cur][brow][colB];
        }
        st[nxt][brow][colA] = (_Float16)v0;
        st[nxt][brow][colB] = (_Float16)v1;
      }
      __syncthreads();  // barrier A: Rp complete, st[cur] reads done

      if (tid < 16 && t < Lown) {
        const float R = ((Rp[tid][0] + Rp[tid][1]) + (Rp[tid][2] + Rp[tid][3])) +
                        ((Rp[tid][4] + Rp[tid][5]) + (Rp[tid][6] + Rp[tid][7]));
        Gown += __logf(Zown) - LOGK;  // G' = G + log(Z/K)
        Zown = Kn * R / Zown;         // Z' = sum st[nxt] = K*R/Z
        iKZ[tid] = Kn / Zown;
      }

      // rotate emission pipeline (off critical chain)
#pragma unroll
      for (int i = 0; i < 8; ++i) pc[i] = __expf(lpn[i]);
      {
        const int tf = (t + 2 < Lmax) ? t + 2 : Lmax - 1;
#pragma unroll
        for (int i = 0; i < 8; ++i) lpn[i] = eb[i][(size_t)tf * Cn];
      }
      __syncthreads();  // barrier B: iKZ update visible before next consume
      cur = nxt;
    }

    if (tid < 16) ws[Bn + b0 + tid] = Gown + __logf(Zown);
  } else {
    // ============ CTC numerator forward (log domain, 1 state/thread) ============
    const int b = bid - 2;
    const int L = clampi(in_lens[b], Sn, Tn);
    const int tl = clampi(tgt_lens[b], 1, Un);

    __shared__ float abuf[2][Sn + 3];  // +2 front pad (NEG), states at [s+2]
    const float* lpb = logp + (size_t)b * Tn * Cn;
    const int* tgtb = targets + b * Un;

    const int s = tid;  // lanes >= Sn idle but barrier-participate
    const bool act = (s < Sn);
    int e = 0;
    bool k = false;
    if (act && (s & 1)) {
      const int uu = (s - 1) >> 1;
      e = clampi(tgtb[uu], 1, Cn - 1);
      if (uu > 0) k = (e != clampi(tgtb[uu - 1], 1, Cn - 1));
    }

    if (act) abuf[0][s + 2] = (s == 0) ? lpb[0] : (s == 1 ? lpb[e] : NEGF);
    if (tid < 2) { abuf[0][tid] = NEGF; abuf[1][tid] = NEGF; }
    float em_cur = lpb[Cn + e];
    float em_mid = lpb[2 * Cn + e];
    __syncthreads();

    int cur = 0;
    for (int t = 1; t < L; ++t) {
      const float* A = abuf[cur];
      if (act) {
        const float x = A[s + 2], y = A[s + 1];
        const float z = k ? A[s] : NEGF;
        abuf[cur ^ 1][s + 2] = lse3(x, y, z) + em_cur;
      }
      em_cur = em_mid;
      const int tf = (t + 2 < L) ? t + 2 : L - 1;
      em_mid = lpb[(size_t)tf * Cn + e];
      __syncthreads();
      cur ^= 1;
    }
    if (tid == 0) {
      const int l = 2 * tl;
      const float x = abuf[cur][l + 2], y = abuf[cur][l + 1];
      const float m = fmaxf(x, y);
      ws[b] = m + __logf(__expf(x - m) + __expf(y - m));
    }
  }
}

__global__ void finalize_kernel(const float* __restrict__ ws,
                                float* __restrict__ out) {
  const int tid = threadIdx.x;  // 64 threads, one wave
  float tot = 0.f, cnt = 0.f;
  if (tid < Bn) {
    const float tv = ws[tid] - ws[Bn + tid];  // num - DEN_SCALE*den
    const bool valid = tv > 0.5f * NEGF;
    tot = valid ? tv : 0.f;
    cnt = valid ? 1.f : 0.f;
  }
#pragma unroll
  for (int off = 32; off >= 1; off >>= 1) {
    tot += __shfl_xor(tot, off, 64);
    cnt += __shfl_xor(cnt, off, 64);
  }
  if (tid == 0) out[0] = -tot / fmaxf(cnt, 1.f);
}

extern "C" void kernel_launch(void* const* d_in, const int* in_sizes, int n_in,
                              void* d_out, int out_size, void* d_ws, size_t ws_size,
                              hipStream_t stream) {
  const float* logp = (const float*)d_in[0];
  const int* targets = (const int*)d_in[1];
  const int* in_lens = (const int*)d_in[2];
  const int* tgt_lens = (const int*)d_in[3];
  const float* trans = (const float*)d_in[4];
  const float* start = (const float*)d_in[5];
  float* ws = (float*)d_ws;
  float* out = (float*)d_out;
  (void)in_sizes; (void)n_in; (void)out_size; (void)ws_size;

  fwd_kernel<<<dim3(2 + Bn), dim3(512), 0, stream>>>(
      logp, targets, in_lens, tgt_lens, trans, start, ws);
  finalize_kernel<<<dim3(1), dim3(64), 0, stream>>>(ws, out);
}

// Round 6
// 1480.244 us; speedup vs baseline: 1.3910x; 1.3910x over previous
//
#include <hip/hip_runtime.h>
#include <stdint.h>
#include <stddef.h>

#define NEGF (-1.0e30f)
#define LOGK 8.31776616672f  // log(4096)

typedef _Float16 f16x8 __attribute__((ext_vector_type(8)));
typedef _Float16 f16x4 __attribute__((ext_vector_type(4)));
typedef float f32x4 __attribute__((ext_vector_type(4)));

constexpr int Bn = 32;
constexpr int Tn = 2000;
constexpr int Cn = 256;
constexpr int Un = 200;
constexpr int Sn = 2 * Un + 1;  // 401
constexpr float Kn = 4096.0f;
constexpr int CP = 264;  // st class-stride (f16): 528B = 33*16B -> uniform bank quads

// Raw workgroup barrier: drain LDS ops only. Global loads stay IN FLIGHT across
// the barrier (R5 killer: __syncthreads' vmcnt(0) put ~900cy HBM latency on the
// 2000-step serial chain). "memory" clobber stops reordering; dependency
// waitcnts for load results are still emitted by the compiler.
#define RAWBAR() __asm__ __volatile__("s_waitcnt lgkmcnt(0)\ns_barrier" ::: "memory")

__device__ __forceinline__ float lse3(float a, float b, float c) {
  float m = fmaxf(fmaxf(a, b), c);
  return m + __logf(__expf(a - m) + __expf(b - m) + __expf(c - m));
}

__device__ __forceinline__ int clampi(int v, int lo, int hi) {
  return v < lo ? lo : (v > hi ? hi : v);
}

// 36 blocks x 256 threads. Blocks 0-3: denominator (8 b each, MFMA-batched).
// Blocks 4-35: CTC numerator (1 b each, 2 states/thread).
__global__ __launch_bounds__(256, 1) void fwd_kernel(
    const float* __restrict__ logp, const int* __restrict__ targets,
    const int* __restrict__ in_lens, const int* __restrict__ tgt_lens,
    const float* __restrict__ trans, const float* __restrict__ start,
    float* __restrict__ ws) {
  const int tid = threadIdx.x;
  const int bid = blockIdx.x;

  if (bid < 4) {
    // ============ denominator: D[j][b] = sum_i E^T[j,i] * st[i,b] ============
    // A = E^T (static, 128 VGPRs/lane); B = st[b][i] (i-contig per b = b128);
    // C output: lane(low=b) holds 4 consecutive classes -> b64 st writes.
    // Produce-layout == consume-layout: no transpose anywhere.
    const int b0 = 8 * bid;
    const int w = tid >> 6;     // wave 0..3: class-tiles Tg = 4w+T
    const int lane = tid & 63;
    const int low = lane & 15;  // n = batch row b (0..7 real, 8..15 dead)
    const int q8 = lane >> 4;   // k-quad / C-row quad

    __shared__ __align__(16) _Float16 stL[2][16][CP];  // exp-domain alpha, f16
    __shared__ __align__(16) float Rp[2][16][12];      // 8 partials + pad

    int Lb = 0;
    if (low < 8) Lb = clampi(in_lens[b0 + low], Sn, Tn);
    int Lmax = Sn;
#pragma unroll
    for (int bb = 0; bb < 8; ++bb)
      Lmax = max(Lmax, clampi(in_lens[b0 + bb], Sn, Tn));

    const int cbase = 64 * w + low;  // class row of A-frags
    const int off0 = 64 * w + 0 * 16 + 4 * q8;
    const int off1 = 64 * w + 1 * 16 + 4 * q8;
    const int off2 = 64 * w + 2 * 16 + 4 * q8;
    const int off3 = 64 * w + 3 * 16 + 4 * q8;

// A-frag (E^T): lane(low=m,q8) holds E^T[class=16Tg+low][i=32KK+8q8+J]
#define E1F(T, KK, J) \
  ((_Float16)__expf(trans[(32 * (KK) + 8 * q8 + (J)) * Cn + cbase + 16 * (T)]))
#define MKE(T, KK)                                                   \
  (f16x8){E1F(T, KK, 0), E1F(T, KK, 1), E1F(T, KK, 2), E1F(T, KK, 3), \
          E1F(T, KK, 4), E1F(T, KK, 5), E1F(T, KK, 6), E1F(T, KK, 7)}
    const f16x8 E0_0 = MKE(0, 0), E0_1 = MKE(0, 1), E0_2 = MKE(0, 2), E0_3 = MKE(0, 3);
    const f16x8 E0_4 = MKE(0, 4), E0_5 = MKE(0, 5), E0_6 = MKE(0, 6), E0_7 = MKE(0, 7);
    const f16x8 E1_0 = MKE(1, 0), E1_1 = MKE(1, 1), E1_2 = MKE(1, 2), E1_3 = MKE(1, 3);
    const f16x8 E1_4 = MKE(1, 4), E1_5 = MKE(1, 5), E1_6 = MKE(1, 6), E1_7 = MKE(1, 7);
    const f16x8 E2_0 = MKE(2, 0), E2_1 = MKE(2, 1), E2_2 = MKE(2, 2), E2_3 = MKE(2, 3);
    const f16x8 E2_4 = MKE(2, 4), E2_5 = MKE(2, 5), E2_6 = MKE(2, 6), E2_7 = MKE(2, 7);
    const f16x8 E3_0 = MKE(3, 0), E3_1 = MKE(3, 1), E3_2 = MKE(3, 2), E3_3 = MKE(3, 3);
    const f16x8 E3_4 = MKE(3, 4), E3_5 = MKE(3, 5), E3_6 = MKE(3, 6), E3_7 = MKE(3, 7);
#undef MKE
#undef E1F

    const float* lpb_my = logp + (size_t)(b0 + ((low < 8) ? low : 0)) * Tn * Cn;

    // ---- init t=0: st = K*exp(start+lp0); Rp[0] = partials of Sigma st_0 ----
    float rsum;
    {
      const float4 s0 = *(const float4*)(start + off0);
      const float4 s1 = *(const float4*)(start + off1);
      const float4 s2 = *(const float4*)(start + off2);
      const float4 s3 = *(const float4*)(start + off3);
      const float4 a0 = *(const float4*)(lpb_my + off0);
      const float4 a1 = *(const float4*)(lpb_my + off1);
      const float4 a2 = *(const float4*)(lpb_my + off2);
      const float4 a3 = *(const float4*)(lpb_my + off3);
      const float live = (low < 8) ? Kn : 0.0f;
      rsum = 0.f;
#define INI(sv, av, off)                                                   \
  {                                                                        \
    float v0 = live * __expf(sv.x + av.x), v1 = live * __expf(sv.y + av.y); \
    float v2 = live * __expf(sv.z + av.z), v3 = live * __expf(sv.w + av.w); \
    rsum += (v0 + v1) + (v2 + v3);                                         \
    f16x4 pk = {(_Float16)v0, (_Float16)v1, (_Float16)v2, (_Float16)v3};   \
    *(f16x4*)&stL[0][low][off] = pk;                                       \
  }
      INI(s0, a0, off0) INI(s1, a1, off1) INI(s2, a2, off2) INI(s3, a3, off3)
#undef INI
      const float r2 = rsum + __shfl_xor(rsum, 32, 64);
      if (q8 < 2) Rp[0][low][4 * q8 + w] = r2;
    }
    float G = -LOGK, kprev = 1.0f;
    float4 ld0 = *(const float4*)(lpb_my + Cn + off0);  // frame 1 emissions
    float4 ld1 = *(const float4*)(lpb_my + Cn + off1);
    float4 ld2 = *(const float4*)(lpb_my + Cn + off2);
    float4 ld3 = *(const float4*)(lpb_my + Cn + off3);
    RAWBAR();

    for (int t = 1; t < Lmax; ++t) {
      const int pr = (t - 1) & 1, pw = t & 1;

      // kappa-path partial reads (overlap MFMA phase)
      const float4 rA = *(const float4*)&Rp[pr][low][0];
      const float4 rB = *(const float4*)&Rp[pr][low][4];

      f32x4 c0 = {0.f, 0.f, 0.f, 0.f}, c1 = {0.f, 0.f, 0.f, 0.f};
      f32x4 c2 = {0.f, 0.f, 0.f, 0.f}, c3 = {0.f, 0.f, 0.f, 0.f};
#define KSTEP(KK, EA, EB, EC, ED)                                          \
  {                                                                        \
    const f16x8 bf = *(const f16x8*)&stL[pr][low][32 * (KK) + 8 * q8];     \
    c0 = __builtin_amdgcn_mfma_f32_16x16x32_f16(EA, bf, c0, 0, 0, 0);      \
    c1 = __builtin_amdgcn_mfma_f32_16x16x32_f16(EB, bf, c1, 0, 0, 0);      \
    c2 = __builtin_amdgcn_mfma_f32_16x16x32_f16(EC, bf, c2, 0, 0, 0);      \
    c3 = __builtin_amdgcn_mfma_f32_16x16x32_f16(ED, bf, c3, 0, 0, 0);      \
  }
      KSTEP(0, E0_0, E1_0, E2_0, E3_0)
      KSTEP(1, E0_1, E1_1, E2_1, E3_1)
      KSTEP(2, E0_2, E1_2, E2_2, E3_2)
      KSTEP(3, E0_3, E1_3, E2_3, E3_3)
      KSTEP(4, E0_4, E1_4, E2_4, E3_4)
      KSTEP(5, E0_5, E1_5, E2_5, E3_5)
      KSTEP(6, E0_6, E1_6, E2_6, E3_6)
      KSTEP(7, E0_7, E1_7, E2_7, E3_7)
#undef KSTEP

      // finish kappa: zeta_t = R_{t-1} * kappa_{t-1}; kappa_t = K/zeta_t
      const float R = ((rA.x + rA.y) + (rA.z + rA.w)) +
                      ((rB.x + rB.y) + (rB.z + rB.w));
      G -= __logf(kprev);
      const float zeta = R * kprev;
      if (t == Lb) ws[Bn + b0 + low] = G + __logf(zeta);  // 16 dup stores, same value
      const float kap = (low < 8) ? Kn * __frcp_rn(zeta) : 0.0f;
      kprev = kap;

      const int tn = (t + 1 < Lmax) ? t + 1 : Lmax - 1;
      rsum = 0.f;
#define TILE(cT, ldT, off)                                                  \
  {                                                                         \
    const float p0 = __expf(ldT.x), p1 = __expf(ldT.y);                     \
    const float p2 = __expf(ldT.z), p3 = __expf(ldT.w);                     \
    const float r0 = cT[0] * p0, r1 = cT[1] * p1;                           \
    const float r2 = cT[2] * p2, r3 = cT[3] * p3;                           \
    rsum += (r0 + r1) + (r2 + r3);                                          \
    f16x4 pk = {(_Float16)(r0 * kap), (_Float16)(r1 * kap),                 \
                (_Float16)(r2 * kap), (_Float16)(r3 * kap)};                \
    *(f16x4*)&stL[pw][low][off] = pk;                                       \
    ldT = *(const float4*)(lpb_my + (size_t)tn * Cn + off);                 \
  }
      TILE(c0, ld0, off0) TILE(c1, ld1, off1) TILE(c2, ld2, off2) TILE(c3, ld3, off3)
#undef TILE

      const float r2 = rsum + __shfl_xor(rsum, 32, 64);
      if (q8 < 2) Rp[pw][low][4 * q8 + w] = r2;
      RAWBAR();
    }

    // epilogue: b's with L == Lmax finish here
    {
      const int pr = (Lmax - 1) & 1;
      const float4 rA = *(const float4*)&Rp[pr][low][0];
      const float4 rB = *(const float4*)&Rp[pr][low][4];
      const float R = ((rA.x + rA.y) + (rA.z + rA.w)) +
                      ((rB.x + rB.y) + (rB.z + rB.w));
      G -= __logf(kprev);
      const float zeta = R * kprev;
      if (Lb == Lmax) ws[Bn + b0 + low] = G + __logf(zeta);
    }
  } else {
    // ============ CTC numerator forward (log domain, 2 states/thread) ============
    const int b = bid - 4;
    const int L = clampi(in_lens[b], Sn, Tn);
    const int tl = clampi(tgt_lens[b], 1, Un);

    __shared__ float abuf[2][Sn + 3];  // +2 front pad (NEG), states at [s+2]
    const float* lpb = logp + (size_t)b * Tn * Cn;
    const int* tgtb = targets + b * Un;

    const int s1 = tid;        // states 0..255
    const int s2 = tid + 256;  // states 256..400 (valid if < Sn)
    int e1 = 0, e2 = 0;
    bool k1 = false, k2 = false;
    if (s1 & 1) {
      const int uu = (s1 - 1) >> 1;
      e1 = clampi(tgtb[uu], 1, Cn - 1);
      if (uu > 0) k1 = (e1 != clampi(tgtb[uu - 1], 1, Cn - 1));
    }
    if ((s2 < Sn) && (s2 & 1)) {
      const int uu = (s2 - 1) >> 1;
      e2 = clampi(tgtb[uu], 1, Cn - 1);
      k2 = (e2 != clampi(tgtb[uu - 1], 1, Cn - 1));  // uu >= 127 > 0 here
    }

    // t = 0 init
    abuf[0][s1 + 2] = (s1 == 0) ? lpb[0] : (s1 == 1 ? lpb[e1] : NEGF);
    if (s2 < Sn) abuf[0][s2 + 2] = NEGF;
    if (tid < 2) { abuf[0][tid] = NEGF; abuf[1][tid] = NEGF; }
    float pe1 = lpb[Cn + e1];  // 2-deep emission pipeline (addresses t-invariant)
    float pe2 = lpb[Cn + e2];
    float pm1 = lpb[2 * Cn + e1];
    float pm2 = lpb[2 * Cn + e2];
    RAWBAR();

    int cur = 0;
    for (int t = 1; t < L; ++t) {
      const float em1 = pe1, em2 = pe2;
      const float* A = abuf[cur];
      float* Bv = abuf[cur ^ 1];
      {
        const float x = A[s1 + 2], y = A[s1 + 1];
        const float z = k1 ? A[s1] : NEGF;
        Bv[s1 + 2] = lse3(x, y, z) + em1;
      }
      if (s2 < Sn) {
        const float x = A[s2 + 2], y = A[s2 + 1];
        const float z = k2 ? A[s2] : NEGF;
        Bv[s2 + 2] = lse3(x, y, z) + em2;
      }
      pe1 = pm1;
      pe2 = pm2;
      const int tf = (t + 2 < L) ? t + 2 : L - 1;
      pm1 = lpb[(size_t)tf * Cn + e1];
      pm2 = lpb[(size_t)tf * Cn + e2];
      RAWBAR();
      cur ^= 1;
    }
    if (tid == 0) {
      const int l = 2 * tl;
      const float x = abuf[cur][l + 2], y = abuf[cur][l + 1];
      const float m = fmaxf(x, y);
      ws[b] = m + __logf(__expf(x - m) + __expf(y - m));
    }
  }
}

__global__ void finalize_kernel(const float* __restrict__ ws,
                                float* __restrict__ out) {
  const int tid = threadIdx.x;  // 64 threads, one wave
  float tot = 0.f, cnt = 0.f;
  if (tid < Bn) {
    const float tv = ws[tid] - ws[Bn + tid];  // num - DEN_SCALE*den
    const bool valid = tv > 0.5f * NEGF;
    tot = valid ? tv : 0.f;
    cnt = valid ? 1.f : 0.f;
  }
#pragma unroll
  for (int off = 32; off >= 1; off >>= 1) {
    tot += __shfl_xor(tot, off, 64);
    cnt += __shfl_xor(cnt, off, 64);
  }
  if (tid == 0) out[0] = -tot / fmaxf(cnt, 1.f);
}

extern "C" void kernel_launch(void* const* d_in, const int* in_sizes, int n_in,
                              void* d_out, int out_size, void* d_ws, size_t ws_size,
                              hipStream_t stream) {
  const float* logp = (const float*)d_in[0];
  const int* targets = (const int*)d_in[1];
  const int* in_lens = (const int*)d_in[2];
  const int* tgt_lens = (const int*)d_in[3];
  const float* trans = (const float*)d_in[4];
  const float* start = (const float*)d_in[5];
  float* ws = (float*)d_ws;
  float* out = (float*)d_out;
  (void)in_sizes; (void)n_in; (void)out_size; (void)ws_size;

  fwd_kernel<<<dim3(4 + Bn), dim3(256), 0, stream>>>(
      logp, targets, in_lens, tgt_lens, trans, start, ws);
  finalize_kernel<<<dim3(1), dim3(64), 0, stream>>>(ws, out);
}